// Round 2
// baseline (545.154 us; speedup 1.0000x reference)
//
#include <hip/hip_runtime.h>
#include <math.h>

#define S      512
#define BATCH  32
#define NDIAG  (2 * S - 1)   // 1023
#define TS     64            // DP tile size (= wave size)
#define NT     (S / TS)      // 8 tiles per dim
#define NPH    (2 * NT - 1)  // 15 tile-diagonal phases
#define LDSP   68            // padded LDS row stride for pairdist
#define INFF   __builtin_huge_valf()

// ---------------------------------------------------------------------------
// Kernel 1: D[b,i,j] = |x_i|^2 + |y_j|^2 - 2<x_i,y_j>, stored anti-diagonally:
//   ws[b][p][i] with p = i + j   (so the DP kernel reads coalesced rows)
// ---------------------------------------------------------------------------
__global__ __launch_bounds__(256) void pairdist_kernel(
    const float* __restrict__ X, const float* __restrict__ Y,
    float* __restrict__ Dd)
{
    const int b   = blockIdx.z;
    const int i0  = blockIdx.y * 64;
    const int j0  = blockIdx.x * 64;
    const int tid = threadIdx.x;

    __shared__ float XsT[64][LDSP];  // [k][i]
    __shared__ float YsT[64][LDSP];  // [k][j]
    __shared__ float x2s[64], y2s[64];

    const float* Xb = X + ((size_t)b * S + i0) * 64;
    const float* Yb = Y + ((size_t)b * S + j0) * 64;

#pragma unroll
    for (int c = 0; c < 4; ++c) {
        int idx = c * 1024 + tid * 4;
        int row = idx >> 6;
        int k   = idx & 63;
        float4 vx = *(const float4*)(Xb + (size_t)row * 64 + k);
        float4 vy = *(const float4*)(Yb + (size_t)row * 64 + k);
        XsT[k + 0][row] = vx.x; XsT[k + 1][row] = vx.y;
        XsT[k + 2][row] = vx.z; XsT[k + 3][row] = vx.w;
        YsT[k + 0][row] = vy.x; YsT[k + 1][row] = vy.y;
        YsT[k + 2][row] = vy.z; YsT[k + 3][row] = vy.w;
    }
    __syncthreads();

    if (tid < 64) {
        float s = 0.f;
#pragma unroll 8
        for (int k = 0; k < 64; ++k) { float v = XsT[k][tid]; s = fmaf(v, v, s); }
        x2s[tid] = s;
    } else if (tid < 128) {
        int r = tid - 64;
        float s = 0.f;
#pragma unroll 8
        for (int k = 0; k < 64; ++k) { float v = YsT[k][r]; s = fmaf(v, v, s); }
        y2s[r] = s;
    }
    __syncthreads();

    const int tx = tid & 15;
    const int ty = tid >> 4;
    float acc[4][4] = {};
#pragma unroll 4
    for (int k = 0; k < 64; ++k) {
        float4 a  = *(const float4*)&XsT[k][ty * 4];
        float4 bb = *(const float4*)&YsT[k][tx * 4];
        float av[4] = {a.x, a.y, a.z, a.w};
        float bv[4] = {bb.x, bb.y, bb.z, bb.w};
#pragma unroll
        for (int r = 0; r < 4; ++r)
#pragma unroll
            for (int c = 0; c < 4; ++c)
                acc[r][c] = fmaf(av[r], bv[c], acc[r][c]);
    }

    float xr[4], yc[4];
#pragma unroll
    for (int r = 0; r < 4; ++r) xr[r] = x2s[ty * 4 + r];
#pragma unroll
    for (int c = 0; c < 4; ++c) yc[c] = y2s[tx * 4 + c];

    float* Db = Dd + (size_t)b * NDIAG * S;
#pragma unroll
    for (int r = 0; r < 4; ++r) {
        int gi = i0 + ty * 4 + r;
#pragma unroll
        for (int c = 0; c < 4; ++c) {
            int gj = j0 + tx * 4 + c;
            int p  = gi + gj;
            Db[(size_t)p * S + gi] = xr[r] + yc[c] - 2.0f * acc[r][c];
        }
    }
}

// ---------------------------------------------------------------------------
// Kernel 2: tiled wavefront soft-DTW DP. One block per batch, wave I owns
// tile-row I. Within a 64x64 tile, lane l owns row l; 127 skewed steps with
// __shfl_up neighbor exchange (no barriers). 15 phases, 1 barrier each.
// Invariants exploited:
//  - dd (i-1,j-1) = previous step's shuffle result (up_prev)
//  - left boundary = lane's own pre-update r_cur entering its first step
//  - left-dd seed  = neighbor's pre-update r_cur via the normal shuffle
//  - corner = T[63] of the same wave's previous tile (register carry)
// Only the top boundary row goes through LDS (double-buffered by phase parity;
// row NT is a permanent INF row for tile-row 0).
// ---------------------------------------------------------------------------
__global__ __launch_bounds__(512) void softdtw_dp_tiled(
    const float* __restrict__ Dd, float* __restrict__ out)
{
    const int b    = blockIdx.x;
    const int tid  = threadIdx.x;
    const int I    = tid >> 6;   // wave id = tile row
    const int lane = tid & 63;

    __shared__ float Btop[2][NT + 1][TS];

    if (tid < 128) Btop[tid >> 6][NT][tid & 63] = INFF;
    __syncthreads();

    const float* __restrict__ Db = Dd + (size_t)b * NDIAG * S;

    float r_cur  = INFF;                      // doubles as left boundary between phases
    float corner = (I == 0) ? 0.0f : INFF;    // R[i0-1][j0-1] for the J==0 tile

    for (int d = 0; d < NPH; ++d) {
        const int J = d - I;
        if (0 <= J && J < NT) {
            const float* __restrict__ Trow =
                (I == 0) ? &Btop[(d - 1) & 1][NT][0] : &Btop[(d - 1) & 1][I - 1][0];
            float* __restrict__ Brow = &Btop[d & 1][I][0];

            // D for step s lives at Db[(64*d + s)*S + 64*I + lane] (coalesced)
            const float* __restrict__ dbase = Db + (size_t)(TS * d) * S + TS * I + lane;

            float q0 = dbase[0];
            float q1 = dbase[(size_t)1 * S];
            float q2 = dbase[(size_t)2 * S];
            float q3 = dbase[(size_t)3 * S];

            float t_prev = corner;     // lane0 dd source: T[s-1], seeded with corner
            float t_cur  = Trow[0];    // lane0 up source: T[s]
            float t_nx   = Trow[1];
            float up_prev = INFF;

            for (int s = 0; s < 2 * TS - 1; ++s) {
                float up_shfl = __shfl_up(r_cur, 1);
                float dd = (lane == 0) ? t_prev : up_prev;
                float up = (lane == 0) ? t_cur  : up_shfl;
                float lf = r_cur;

                float m   = fminf(dd, fminf(up, lf));
                float e   = __expf(m - dd) + __expf(m - up) + __expf(m - lf);
                float sm  = m - __logf(e);
                float val = q0 + sm;

                bool active = ((unsigned)(s - lane)) <= (unsigned)(TS - 1);
                r_cur = active ? val : r_cur;

                if (lane == TS - 1 && s >= TS - 1) Brow[s - (TS - 1)] = r_cur;

                up_prev = up_shfl;
                t_prev  = t_cur;
                t_cur   = t_nx;
                int ts2 = s + 2; ts2 = ts2 > TS - 1 ? TS - 1 : ts2;
                t_nx = Trow[ts2];

                q0 = q1; q1 = q2; q2 = q3;
                int s4 = s + 4; s4 = s4 > 2 * TS - 2 ? 2 * TS - 2 : s4;
                q3 = dbase[(size_t)s4 * S];
            }
            corner = t_cur;   // = T[63] -> corner of this wave's next tile
        }
        __syncthreads();
    }

    if (tid == S - 1) out[b] = r_cur;   // R[511][511]
}

// ---------------------------------------------------------------------------
extern "C" void kernel_launch(void* const* d_in, const int* in_sizes, int n_in,
                              void* d_out, int out_size, void* d_ws, size_t ws_size,
                              hipStream_t stream)
{
    const float* X = (const float*)d_in[0];
    const float* Y = (const float*)d_in[1];
    float* out = (float*)d_out;
    float* Dd  = (float*)d_ws;   // 32*1023*512*4 = ~64 MiB

    dim3 g1(S / 64, S / 64, BATCH);
    pairdist_kernel<<<g1, 256, 0, stream>>>(X, Y, Dd);

    softdtw_dp_tiled<<<BATCH, 512, 0, stream>>>(Dd, out);
}

// Round 3
// 367.899 us; speedup vs baseline: 1.4818x; 1.4818x over previous
//
#include <hip/hip_runtime.h>
#include <math.h>

#define S      512
#define BATCH  32
#define TS     64            // tile size = wave size
#define NT     (S / TS)      // 8 tile rows/cols
#define NPH    (2 * NT - 1)  // 15 phases
#define NGRP   256           // diagonal groups of 4: p in [0,1023) -> p>>2 in [0,256)
#define LDSP   68
#define INFF   __builtin_huge_valf()

// wave-wide shift-up-by-1 via DPP wave_shr:1 (VALU latency, no DS pipe).
// lane i gets src[i-1]; lane 0 gets `old` (bound_ctrl=false keeps old).
__device__ __forceinline__ float dpp_shr1(float src, float old) {
    return __int_as_float(__builtin_amdgcn_update_dpp(
        __float_as_int(old), __float_as_int(src), 0x138, 0xf, 0xf, false));
}

__device__ __forceinline__ float lane_bcast(float v, int l) {
    return __int_as_float(__builtin_amdgcn_readlane(__float_as_int(v), l));
}

// ---------------------------------------------------------------------------
// Kernel 1: D[b,i,j] = |x_i|^2 + |y_j|^2 - 2<x_i,y_j>, stored in 4-wide
// diagonal groups:  ws[b][p>>2][i][p&3]  with p = i + j, so the DP kernel
// reads one float4 (4 consecutive diagonals) per lane, coalesced across i.
// ---------------------------------------------------------------------------
__global__ __launch_bounds__(256) void pairdist_kernel(
    const float* __restrict__ X, const float* __restrict__ Y,
    float* __restrict__ Dd)
{
    const int b   = blockIdx.z;
    const int i0  = blockIdx.y * 64;
    const int j0  = blockIdx.x * 64;
    const int tid = threadIdx.x;

    __shared__ float XsT[64][LDSP];  // [k][i]
    __shared__ float YsT[64][LDSP];  // [k][j]
    __shared__ float x2s[64], y2s[64];

    const float* Xb = X + ((size_t)b * S + i0) * 64;
    const float* Yb = Y + ((size_t)b * S + j0) * 64;

#pragma unroll
    for (int c = 0; c < 4; ++c) {
        int idx = c * 1024 + tid * 4;
        int row = idx >> 6;
        int k   = idx & 63;
        float4 vx = *(const float4*)(Xb + (size_t)row * 64 + k);
        float4 vy = *(const float4*)(Yb + (size_t)row * 64 + k);
        XsT[k + 0][row] = vx.x; XsT[k + 1][row] = vx.y;
        XsT[k + 2][row] = vx.z; XsT[k + 3][row] = vx.w;
        YsT[k + 0][row] = vy.x; YsT[k + 1][row] = vy.y;
        YsT[k + 2][row] = vy.z; YsT[k + 3][row] = vy.w;
    }
    __syncthreads();

    if (tid < 64) {
        float s = 0.f;
#pragma unroll 8
        for (int k = 0; k < 64; ++k) { float v = XsT[k][tid]; s = fmaf(v, v, s); }
        x2s[tid] = s;
    } else if (tid < 128) {
        int r = tid - 64;
        float s = 0.f;
#pragma unroll 8
        for (int k = 0; k < 64; ++k) { float v = YsT[k][r]; s = fmaf(v, v, s); }
        y2s[r] = s;
    }
    __syncthreads();

    const int tx = tid & 15;
    const int ty = tid >> 4;
    float acc[4][4] = {};
#pragma unroll 4
    for (int k = 0; k < 64; ++k) {
        float4 a  = *(const float4*)&XsT[k][ty * 4];
        float4 bb = *(const float4*)&YsT[k][tx * 4];
        float av[4] = {a.x, a.y, a.z, a.w};
        float bv[4] = {bb.x, bb.y, bb.z, bb.w};
#pragma unroll
        for (int r = 0; r < 4; ++r)
#pragma unroll
            for (int c = 0; c < 4; ++c)
                acc[r][c] = fmaf(av[r], bv[c], acc[r][c]);
    }

    float xr[4], yc[4];
#pragma unroll
    for (int r = 0; r < 4; ++r) xr[r] = x2s[ty * 4 + r];
#pragma unroll
    for (int c = 0; c < 4; ++c) yc[c] = y2s[tx * 4 + c];

    float* Db = Dd + (size_t)b * (NGRP * S * 4);
#pragma unroll
    for (int r = 0; r < 4; ++r) {
        int gi = i0 + ty * 4 + r;
#pragma unroll
        for (int c = 0; c < 4; ++c) {
            int gj = j0 + tx * 4 + c;
            int p  = gi + gj;
            Db[((size_t)(p >> 2) * S + gi) * 4 + (p & 3)] =
                xr[r] + yc[c] - 2.0f * acc[r][c];
        }
    }
}

// ---------------------------------------------------------------------------
// Kernel 2: tiled wavefront soft-DTW DP, DPP edition.
// One block/batch; wave I owns tile-row I; lane l owns row 64I+l.
// 15 phases, 1 barrier each; 128 steps/phase.
// Per step: up = dpp_wave_shr1(r_cur, old=T[s]) gives both the neighbor value
// and the lane-0 top boundary; dd = previous step's up; lf = r_cur.
// Top boundary row lives in a register (treg, lane l = T[l]), broadcast via
// readlane. D streamed as float4 (4 diagonals) with a 4-deep prefetch queue
// (16-step lookahead covers L2/L3 latency).
// ---------------------------------------------------------------------------
__global__ __launch_bounds__(512) void softdtw_dp_dpp(
    const float* __restrict__ Dd, float* __restrict__ out)
{
    const int b    = blockIdx.x;
    const int tid  = threadIdx.x;
    const int I    = tid >> 6;   // wave id = tile row
    const int lane = tid & 63;

    __shared__ float Btop[2][NT + 1][TS];
    if (tid < 128) Btop[tid >> 6][NT][tid & 63] = INFF;  // virtual INF top row
    __syncthreads();

    const float4* __restrict__ Dbat =
        (const float4*)(Dd + (size_t)b * (NGRP * S * 4));

    float r_cur  = INFF;                     // carries left boundary between phases
    float corner = (I == 0) ? 0.0f : INFF;   // R[64I-1][64J-1] seed for J==0

    for (int d = 0; d < NPH; ++d) {
        const int J = d - I;
        if (0 <= J && J < NT) {
            const int prow = (I == 0) ? NT : (I - 1);
            float treg = Btop[(d + 1) & 1][prow][lane];   // T[l] in lane l
            float* __restrict__ Brow = &Btop[d & 1][I][0];

            // lane's D stream: group g = 16d+u, row 64I+lane, components p&3
            const float4* __restrict__ qp =
                Dbat + (size_t)(16 * d) * S + (TS * I + lane);
            float4 qbuf[4];
#pragma unroll
            for (int u = 0; u < 4; ++u) qbuf[u] = qp[(size_t)u * S];

            // seed dd: lane0 <- corner, lane i <- r_cur[i-1] (phase-entry vals)
            float up_prev = dpp_shr1(r_cur, corner);

#pragma unroll 4
            for (int u = 0; u < 32; ++u) {
                float4 q = qbuf[u & 3];
                int un = (u + 4 < 32) ? (u + 4) : 31;
                qbuf[u & 3] = qp[(size_t)un * S];

#pragma unroll
                for (int j = 0; j < 4; ++j) {
                    const int s  = 4 * u + j;
                    const int sc = (s < TS - 1) ? s : (TS - 1);
                    float ts  = lane_bcast(treg, sc);       // T[s] (uniform)
                    float up  = dpp_shr1(r_cur, ts);        // lane0 <- T[s]
                    float dd  = up_prev;
                    float lf  = r_cur;
                    float m   = fminf(up, fminf(dd, lf));
                    float e   = __expf(m - dd) + __expf(m - up) + __expf(m - lf);
                    float val = ((j == 0) ? q.x : (j == 1) ? q.y
                                 : (j == 2) ? q.z : q.w)
                                + (m - __logf(e));
                    bool act  = ((unsigned)(s - lane)) <= (unsigned)(TS - 1);
                    r_cur = act ? val : r_cur;
                    if (lane == TS - 1 && ((unsigned)(s - (TS - 1))) <= (unsigned)(TS - 1))
                        Brow[s - (TS - 1)] = r_cur;
                    up_prev = up;
                }
            }
            corner = lane_bcast(treg, TS - 1);   // T[63] -> next tile's corner
        }
        __syncthreads();
    }

    if (tid == S - 1) out[b] = r_cur;   // R[511][511]
}

// ---------------------------------------------------------------------------
extern "C" void kernel_launch(void* const* d_in, const int* in_sizes, int n_in,
                              void* d_out, int out_size, void* d_ws, size_t ws_size,
                              hipStream_t stream)
{
    const float* X = (const float*)d_in[0];
    const float* Y = (const float*)d_in[1];
    float* out = (float*)d_out;
    float* Dd  = (float*)d_ws;   // 32 * 256*512*4 floats = 64 MiB

    dim3 g1(S / 64, S / 64, BATCH);
    pairdist_kernel<<<g1, 256, 0, stream>>>(X, Y, Dd);

    softdtw_dp_dpp<<<BATCH, 512, 0, stream>>>(Dd, out);
}